// Round 6
// baseline (189.914 us; speedup 1.0000x reference)
//
#include <hip/hip_runtime.h>

// (B,N,DIN,DE,NH,DK) = (4,256,128,64,8,16). Inputs f32, output f32.
#define BB   4
#define NN   256
#define DIN  128
#define DE   64
#define NH   8
#define DK   16
#define CC   128   // NH*DK

typedef __attribute__((ext_vector_type(8))) short short8;   // 8 bf16 = 4 VGPRs
typedef __attribute__((ext_vector_type(4))) float f32x4;

// f32 -> bf16 bits, round-to-nearest-even
__device__ __forceinline__ unsigned short f2bfu(float f) {
    union { float f; unsigned int i; } v; v.f = f;
    unsigned int x = v.i;
    x += 0x7FFFu + ((x >> 16) & 1u);
    return (unsigned short)(x >> 16);
}

// ---------------------------------------------------------------------------
// QKV (+merged wprep): blocks 0..255 compute Q/K/Vt (4 rows each);
// blocks 256..263 convert WE/WE2 into MFMA B-fragment order (wfrag).
// Vt layout: Vt[(b*CC + c)*NN + j]  (column-major per batch, for float4 j-reads)
// ---------------------------------------------------------------------------
__global__ __launch_bounds__(256) void qkv_kernel(
    const float* __restrict__ h, const float* __restrict__ WQ,
    const float* __restrict__ WK, const float* __restrict__ WV,
    const float* __restrict__ WE, const float* __restrict__ WE2,
    float* __restrict__ Qw, float* __restrict__ Kw, float* __restrict__ Vt,
    unsigned short* __restrict__ wfrag)
{
    const int t = threadIdx.x;

    if (blockIdx.x >= 256) {             // ---- wprep part ----
        const int tid  = (blockIdx.x - 256) * 256 + t;   // 0..2047
        const int m    = tid >> 10;
        const int g    = (tid >> 7) & 7;
        const int ks   = (tid >> 6) & 1;
        const int lane = tid & 63;
        const int q4 = lane >> 4, l15 = lane & 15;
        const float* W = m ? WE2 : WE;
        union { uint4 u; unsigned short s[8]; } pk;
        #pragma unroll
        for (int ii = 0; ii < 8; ++ii) {
            const int d = ks * 32 + q4 * 8 + ii;
            pk.s[ii] = f2bfu(W[d * CC + g * 16 + l15]);
        }
        ((uint4*)wfrag)[tid] = pk.u;
        return;
    }

    __shared__ float hsh[4 * DIN];       // 2 KB
    __shared__ float psum[4 * 1536];     // 24 KB
    const int r0 = blockIdx.x * 4;

    hsh[t]       = h[(size_t)r0 * DIN + t];
    hsh[256 + t] = h[(size_t)r0 * DIN + 256 + t];
    __syncthreads();

    const int cp  = t & 63;              // channel pair: c = 2cp, 2cp+1
    const int qtr = t >> 6;              // d in [qtr*32, qtr*32+32)
    float aq[4][2], ak[4][2], av[4][2];
    #pragma unroll
    for (int r = 0; r < 4; ++r)
        aq[r][0]=aq[r][1]=ak[r][0]=ak[r][1]=av[r][0]=av[r][1]=0.f;

    #pragma unroll 4
    for (int dd = 0; dd < 32; ++dd) {
        const int d = qtr * 32 + dd;
        const float2 fq = ((const float2*)WQ)[d * 64 + cp];
        const float2 fk = ((const float2*)WK)[d * 64 + cp];
        const float2 fv = ((const float2*)WV)[d * 64 + cp];
        #pragma unroll
        for (int r = 0; r < 4; ++r) {
            const float hd = hsh[r * DIN + d];
            aq[r][0] = fmaf(hd, fq.x, aq[r][0]); aq[r][1] = fmaf(hd, fq.y, aq[r][1]);
            ak[r][0] = fmaf(hd, fk.x, ak[r][0]); ak[r][1] = fmaf(hd, fk.y, ak[r][1]);
            av[r][0] = fmaf(hd, fv.x, av[r][0]); av[r][1] = fmaf(hd, fv.y, av[r][1]);
        }
    }
    float* pq = psum + qtr * 1536;
    #pragma unroll
    for (int r = 0; r < 4; ++r) {
        pq[r*384       + 2*cp] = aq[r][0]; pq[r*384       + 2*cp+1] = aq[r][1];
        pq[r*384 + 128 + 2*cp] = ak[r][0]; pq[r*384 + 128 + 2*cp+1] = ak[r][1];
        pq[r*384 + 256 + 2*cp] = av[r][0]; pq[r*384 + 256 + 2*cp+1] = av[r][1];
    }
    __syncthreads();

    const int b  = r0 >> 8;              // uniform for the 4 rows
    const int j0 = r0 & 255;
    #pragma unroll
    for (int k = 0; k < 6; ++k) {
        const int o = k * 256 + t;               // 0..1535
        float v = psum[o] + psum[1536 + o] + psum[3072 + o] + psum[4608 + o];
        const int r   = o / 384;
        const int mc  = o - r * 384;
        const int mat = mc >> 7;
        const int c   = mc & 127;
        if      (mat == 0) Qw[(size_t)(r0 + r) * CC + c] = v;
        else if (mat == 1) Kw[(size_t)(r0 + r) * CC + c] = v * 0.25f;  // DK^-0.5
        else               Vt[((size_t)(b * CC) + c) * NN + j0 + r] = v;
    }
}

// ---------------------------------------------------------------------------
// Fused attention. One block (4 waves) per (b,i). e processed in two 128-j
// half-tiles (esh 16K) + qk_sh[h][j] 8K + 1.5K -> 25.5 KB -> 6 blocks/CU.
//
// MFMA 16x16x32 bf16 layouts (HW-verified rounds 3-5):
//   A: lane holds A[m=lane&15][k=(lane>>4)*8+ii]
//   B: lane holds B[k=(lane>>4)*8+ii][n=lane&15]
//   C/D: col=lane&15, row=(lane>>4)*4+reg
// ---------------------------------------------------------------------------
__global__ __launch_bounds__(256, 6) void attn_kernel(
    const float* __restrict__ e, const float* __restrict__ maskp,
    const unsigned short* __restrict__ wfrag,
    const float* __restrict__ Qw, const float* __restrict__ Kw,
    const float* __restrict__ Vt, float* __restrict__ out)
{
    __shared__ __align__(16) unsigned short esh[128 * DE];  // 16 KB, swizzled
    __shared__ float qk_sh[NH * NN];                        // 8 KB, [h][j]
    __shared__ float msk_sh[NN];                            // 1 KB
    __shared__ float qrow_sh[CC];                           // 0.5 KB

    const int row  = blockIdx.x;
    const int b    = row >> 8, i = row & 255;
    const int t    = threadIdx.x;
    const int wave = t >> 6, lane = t & 63;
    const int q4   = lane >> 4;
    const int l15  = lane & 15;

    const float4* esrc = (const float4*)(e + (size_t)row * NN * DE);
    uint4* edst = (uint4*)esh;

    // --- B-fragments straight from global (L2-hot) ---
    short8 bfrag[2][2][2];
    {
        const uint4* wf = (const uint4*)wfrag;
        #pragma unroll
        for (int m = 0; m < 2; ++m)
        #pragma unroll
        for (int ct = 0; ct < 2; ++ct) {
            const int g = wave * 2 + ct;
            #pragma unroll
            for (int ks = 0; ks < 2; ++ks) {
                union { uint4 u; short8 s8; } cv;
                cv.u = wf[((m * 8 + g) * 2 + ks) * 64 + lane];
                bfrag[m][ct][ks] = cv.s8;
            }
        }
    }

    if (t < CC) qrow_sh[t] = Qw[(size_t)row * CC + t];
    msk_sh[t] = maskp[b * NN + t];

    // --- stage half 0: e rows 0..127 -> bf16, XOR-swizzled 16B chunks ---
    #pragma unroll
    for (int r = 0; r < 4; ++r) {
        const int cidx = r * 256 + t;            // chunk 0..1023 within half
        const int j = cidx >> 3, ch = cidx & 7;
        const float4 f0 = esrc[2 * cidx];
        const float4 f1 = esrc[2 * cidx + 1];
        union { uint4 u; unsigned short s[8]; } pk;
        pk.s[0]=f2bfu(f0.x); pk.s[1]=f2bfu(f0.y); pk.s[2]=f2bfu(f0.z); pk.s[3]=f2bfu(f0.w);
        pk.s[4]=f2bfu(f1.x); pk.s[5]=f2bfu(f1.y); pk.s[6]=f2bfu(f1.z); pk.s[7]=f2bfu(f1.w);
        edst[j * 8 + (ch ^ (j & 7))] = pk.u;
    }
    __syncthreads();                             // b1: qrow/msk/esh0 visible

    // --- qk[h][j] for ALL 256 j, full f32 (thread t = j) ---
    {
        const float4* kr = (const float4*)(Kw + (size_t)(b * NN + t) * CC);
        #pragma unroll
        for (int hh = 0; hh < NH; ++hh) {
            float s = 0.f;
            #pragma unroll
            for (int p = 0; p < 4; ++p) {
                const float4 kv = kr[hh * 4 + p];
                const int qb = hh * 16 + p * 4;
                s += kv.x * qrow_sh[qb]     + kv.y * qrow_sh[qb + 1]
                   + kv.z * qrow_sh[qb + 2] + kv.w * qrow_sh[qb + 3];
            }
            qk_sh[hh * 256 + t] = s;             // stride-1 across t: no conflicts
        }
    }
    __syncthreads();                             // b2: qk visible

    const float mi = msk_sh[i];
    float acc[2] = {0.f, 0.f}, dnm[2] = {0.f, 0.f};
    const short8* ep = (const short8*)esh;

    #pragma unroll
    for (int hf = 0; hf < 2; ++hf) {
        if (hf == 1) {
            __syncthreads();                     // b3: done reading esh half0
            #pragma unroll
            for (int r = 0; r < 4; ++r) {        // stage half 1 (rows 128..255)
                const int cidx = r * 256 + t;
                const int j = cidx >> 3, ch = cidx & 7;
                const float4 f0 = esrc[2048 + 2 * cidx];
                const float4 f1 = esrc[2048 + 2 * cidx + 1];
                union { uint4 u; unsigned short s[8]; } pk;
                pk.s[0]=f2bfu(f0.x); pk.s[1]=f2bfu(f0.y); pk.s[2]=f2bfu(f0.z); pk.s[3]=f2bfu(f0.w);
                pk.s[4]=f2bfu(f1.x); pk.s[5]=f2bfu(f1.y); pk.s[6]=f2bfu(f1.z); pk.s[7]=f2bfu(f1.w);
                edst[j * 8 + (ch ^ (j & 7))] = pk.u;
            }
            __syncthreads();                     // b4: esh half1 visible
        }
        #pragma unroll 2
        for (int s = 0; s < 8; ++s) {
            const int ja = s * 16 + l15;
            const short8 a0 = ep[ja * 8 + ((q4    ) ^ (ja & 7))];  // d 0..31
            const short8 a1 = ep[ja * 8 + ((q4 + 4) ^ (ja & 7))];  // d 32..63
            #pragma unroll
            for (int ct = 0; ct < 2; ++ct) {
                const int g = wave * 2 + ct;
                f32x4 s2 = {0.f,0.f,0.f,0.f}, eE = {0.f,0.f,0.f,0.f};
                s2 = __builtin_amdgcn_mfma_f32_16x16x32_bf16(a0, bfrag[1][ct][0], s2, 0,0,0);
                s2 = __builtin_amdgcn_mfma_f32_16x16x32_bf16(a1, bfrag[1][ct][1], s2, 0,0,0);
                eE = __builtin_amdgcn_mfma_f32_16x16x32_bf16(a0, bfrag[0][ct][0], eE, 0,0,0);
                eE = __builtin_amdgcn_mfma_f32_16x16x32_bf16(a1, bfrag[0][ct][1], eE, 0,0,0);
                // V[j0..j0+3][c] as one float4 from Vt
                const int j0 = hf * 128 + s * 16 + q4 * 4;
                const float4 v4 = *(const float4*)
                    (Vt + ((size_t)(b * CC) + g * 16 + l15) * NN + j0);
                #pragma unroll
                for (int r = 0; r < 4; ++r) {
                    const int jr = j0 + r;
                    float sc = qk_sh[g * 256 + jr] + s2[r];
                    sc = fminf(5.f, fmaxf(-5.f, sc));
                    const float p  = __expf(sc);
                    const float mm = mi * msk_sh[jr];
                    const float s1 = p * mm;             // mask^1 -> denom
                    dnm[ct] += s1;
                    const float vv = (r==0)?v4.x:(r==1)?v4.y:(r==2)?v4.z:v4.w;
                    acc[ct] = fmaf(s1 * mm, vv + eE[r], acc[ct]);  // mask^2
                }
            }
        }
    }

    // reduce over quad groups (lanes l, l^16, l^32, l^48 share a column)
    #pragma unroll
    for (int ct = 0; ct < 2; ++ct) {
        float a = acc[ct], d = dnm[ct];
        a += __shfl_xor(a, 16); a += __shfl_xor(a, 32);
        d += __shfl_xor(d, 16); d += __shfl_xor(d, 32);
        acc[ct] = a; dnm[ct] = d;
    }
    if (lane < 32) {
        const int ct = lane >> 4;
        out[(size_t)row * CC + wave * 32 + lane] = acc[ct] / fmaxf(dnm[ct], 1e-6f);
    }
}

extern "C" void kernel_launch(void* const* d_in, const int* in_sizes, int n_in,
                              void* d_out, int out_size, void* d_ws, size_t ws_size,
                              hipStream_t stream)
{
    const float* h    = (const float*)d_in[0];
    const float* e    = (const float*)d_in[1];
    const float* mask = (const float*)d_in[2];
    const float* WQ   = (const float*)d_in[3];
    const float* WK   = (const float*)d_in[4];
    const float* WV   = (const float*)d_in[5];
    const float* WE   = (const float*)d_in[6];
    const float* WE2  = (const float*)d_in[7];

    unsigned short* wfrag = (unsigned short*)d_ws;          // 32 KB
    float* Qw = (float*)((char*)d_ws + 32768);              // 512 KB
    float* Kw = Qw + BB * NN * CC;                          // 512 KB
    float* Vt = Kw + BB * NN * CC;                          // 512 KB (transposed)

    qkv_kernel <<<264,   256, 0, stream>>>(h, WQ, WK, WV, WE, WE2,
                                           Qw, Kw, Vt, wfrag);
    attn_kernel<<<BB*NN, 256, 0, stream>>>(e, mask, wfrag, Qw, Kw, Vt,
                                           (float*)d_out);
}

// Round 7
// 148.100 us; speedup vs baseline: 1.2823x; 1.2823x over previous
//
#include <hip/hip_runtime.h>

// (B,N,DIN,DE,NH,DK) = (4,256,128,64,8,16). Inputs f32, output f32.
#define BB   4
#define NN   256
#define DIN  128
#define DE   64
#define NH   8
#define DK   16
#define CC   128   // NH*DK

typedef __attribute__((ext_vector_type(8))) short short8;   // 8 bf16 = 4 VGPRs
typedef __attribute__((ext_vector_type(4))) float f32x4;

// f32 -> bf16 bits, round-to-nearest-even
__device__ __forceinline__ unsigned short f2bfu(float f) {
    union { float f; unsigned int i; } v; v.f = f;
    unsigned int x = v.i;
    x += 0x7FFFu + ((x >> 16) & 1u);
    return (unsigned short)(x >> 16);
}

// ---------------------------------------------------------------------------
// QKV (+merged wprep): blocks 0..255 compute Q/K/Vt (4 rows each);
// blocks 256..263 convert WE/WE2 into MFMA B-fragment order (wfrag).
// Vt layout: Vt[(b*CC + c)*NN + j]
// ---------------------------------------------------------------------------
__global__ __launch_bounds__(256) void qkv_kernel(
    const float* __restrict__ h, const float* __restrict__ WQ,
    const float* __restrict__ WK, const float* __restrict__ WV,
    const float* __restrict__ WE, const float* __restrict__ WE2,
    float* __restrict__ Qw, float* __restrict__ Kw, float* __restrict__ Vt,
    unsigned short* __restrict__ wfrag)
{
    const int t = threadIdx.x;

    if (blockIdx.x >= 256) {             // ---- wprep part ----
        const int tid  = (blockIdx.x - 256) * 256 + t;   // 0..2047
        const int m    = tid >> 10;
        const int g    = (tid >> 7) & 7;
        const int ks   = (tid >> 6) & 1;
        const int lane = tid & 63;
        const int q4 = lane >> 4, l15 = lane & 15;
        const float* W = m ? WE2 : WE;
        union { uint4 u; unsigned short s[8]; } pk;
        #pragma unroll
        for (int ii = 0; ii < 8; ++ii) {
            const int d = ks * 32 + q4 * 8 + ii;
            pk.s[ii] = f2bfu(W[d * CC + g * 16 + l15]);
        }
        ((uint4*)wfrag)[tid] = pk.u;
        return;
    }

    __shared__ float hsh[4 * DIN];       // 2 KB
    __shared__ float psum[4 * 1536];     // 24 KB
    const int r0 = blockIdx.x * 4;

    hsh[t]       = h[(size_t)r0 * DIN + t];
    hsh[256 + t] = h[(size_t)r0 * DIN + 256 + t];
    __syncthreads();

    const int cp  = t & 63;              // channel pair: c = 2cp, 2cp+1
    const int qtr = t >> 6;              // d in [qtr*32, qtr*32+32)
    float aq[4][2], ak[4][2], av[4][2];
    #pragma unroll
    for (int r = 0; r < 4; ++r)
        aq[r][0]=aq[r][1]=ak[r][0]=ak[r][1]=av[r][0]=av[r][1]=0.f;

    #pragma unroll 4
    for (int dd = 0; dd < 32; ++dd) {
        const int d = qtr * 32 + dd;
        const float2 fq = ((const float2*)WQ)[d * 64 + cp];
        const float2 fk = ((const float2*)WK)[d * 64 + cp];
        const float2 fv = ((const float2*)WV)[d * 64 + cp];
        #pragma unroll
        for (int r = 0; r < 4; ++r) {
            const float hd = hsh[r * DIN + d];
            aq[r][0] = fmaf(hd, fq.x, aq[r][0]); aq[r][1] = fmaf(hd, fq.y, aq[r][1]);
            ak[r][0] = fmaf(hd, fk.x, ak[r][0]); ak[r][1] = fmaf(hd, fk.y, ak[r][1]);
            av[r][0] = fmaf(hd, fv.x, av[r][0]); av[r][1] = fmaf(hd, fv.y, av[r][1]);
        }
    }
    float* pq = psum + qtr * 1536;
    #pragma unroll
    for (int r = 0; r < 4; ++r) {
        pq[r*384       + 2*cp] = aq[r][0]; pq[r*384       + 2*cp+1] = aq[r][1];
        pq[r*384 + 128 + 2*cp] = ak[r][0]; pq[r*384 + 128 + 2*cp+1] = ak[r][1];
        pq[r*384 + 256 + 2*cp] = av[r][0]; pq[r*384 + 256 + 2*cp+1] = av[r][1];
    }
    __syncthreads();

    const int b  = r0 >> 8;
    const int j0 = r0 & 255;
    #pragma unroll
    for (int k = 0; k < 6; ++k) {
        const int o = k * 256 + t;               // 0..1535
        float v = psum[o] + psum[1536 + o] + psum[3072 + o] + psum[4608 + o];
        const int r   = o / 384;
        const int mc  = o - r * 384;
        const int mat = mc >> 7;
        const int c   = mc & 127;
        if      (mat == 0) Qw[(size_t)(r0 + r) * CC + c] = v;
        else if (mat == 1) Kw[(size_t)(r0 + r) * CC + c] = v * 0.25f;  // DK^-0.5
        else               Vt[((size_t)(b * CC) + c) * NN + j0 + r] = v;
    }
}

// ---------------------------------------------------------------------------
// Fused attention. One block (4 waves) per (b,i). esh half-tiles 16K +
// qk_sh[h][j] 8K + 1.5K = 25.5 KB. __launch_bounds__(256,5): VGPR cap ~102 —
// round-6's (256,6) cap collapsed the allocator to 40 VGPR + 46 MB scratch
// spill traffic; never pin below natural use (~84).
//
// MFMA 16x16x32 bf16 layouts (HW-verified rounds 3-5):
//   A: lane holds A[m=lane&15][k=(lane>>4)*8+ii]
//   B: lane holds B[k=(lane>>4)*8+ii][n=lane&15]
//   C/D: col=lane&15, row=(lane>>4)*4+reg
// ---------------------------------------------------------------------------
__global__ __launch_bounds__(256, 5) void attn_kernel(
    const float* __restrict__ e, const float* __restrict__ maskp,
    const unsigned short* __restrict__ wfrag,
    const float* __restrict__ Qw, const float* __restrict__ Kw,
    const float* __restrict__ Vt, float* __restrict__ out)
{
    __shared__ __align__(16) unsigned short esh[128 * DE];  // 16 KB, swizzled
    __shared__ float qk_sh[NH * NN];                        // 8 KB, [h][j]
    __shared__ float msk_sh[NN];                            // 1 KB
    __shared__ float qrow_sh[CC];                           // 0.5 KB

    const int row  = blockIdx.x;
    const int b    = row >> 8, i = row & 255;
    const int t    = threadIdx.x;
    const int wave = t >> 6, lane = t & 63;
    const int q4   = lane >> 4;
    const int l15  = lane & 15;

    const float4* esrc = (const float4*)(e + (size_t)row * NN * DE);
    uint4* edst = (uint4*)esh;

    // --- B-fragments straight from global (L2-hot) ---
    short8 bfrag[2][2][2];
    {
        const uint4* wf = (const uint4*)wfrag;
        #pragma unroll
        for (int m = 0; m < 2; ++m)
        #pragma unroll
        for (int ct = 0; ct < 2; ++ct) {
            const int g = wave * 2 + ct;
            #pragma unroll
            for (int ks = 0; ks < 2; ++ks) {
                union { uint4 u; short8 s8; } cv;
                cv.u = wf[((m * 8 + g) * 2 + ks) * 64 + lane];
                bfrag[m][ct][ks] = cv.s8;
            }
        }
    }

    if (t < CC) qrow_sh[t] = Qw[(size_t)row * CC + t];
    msk_sh[t] = maskp[b * NN + t];

    // --- stage half 0: e rows 0..127 -> bf16, XOR-swizzled 16B chunks ---
    #pragma unroll
    for (int r = 0; r < 4; ++r) {
        const int cidx = r * 256 + t;            // chunk 0..1023 within half
        const int j = cidx >> 3, ch = cidx & 7;
        const float4 f0 = esrc[2 * cidx];
        const float4 f1 = esrc[2 * cidx + 1];
        union { uint4 u; unsigned short s[8]; } pk;
        pk.s[0]=f2bfu(f0.x); pk.s[1]=f2bfu(f0.y); pk.s[2]=f2bfu(f0.z); pk.s[3]=f2bfu(f0.w);
        pk.s[4]=f2bfu(f1.x); pk.s[5]=f2bfu(f1.y); pk.s[6]=f2bfu(f1.z); pk.s[7]=f2bfu(f1.w);
        edst[j * 8 + (ch ^ (j & 7))] = pk.u;
    }
    __syncthreads();                             // b1: qrow/msk/esh0 visible

    // --- qk[h][j] for ALL 256 j, full f32 (thread t = j) ---
    {
        const float4* kr = (const float4*)(Kw + (size_t)(b * NN + t) * CC);
        #pragma unroll
        for (int hh = 0; hh < NH; ++hh) {
            float s = 0.f;
            #pragma unroll
            for (int p = 0; p < 4; ++p) {
                const float4 kv = kr[hh * 4 + p];
                const int qb = hh * 16 + p * 4;
                s += kv.x * qrow_sh[qb]     + kv.y * qrow_sh[qb + 1]
                   + kv.z * qrow_sh[qb + 2] + kv.w * qrow_sh[qb + 3];
            }
            qk_sh[hh * 256 + t] = s;             // stride-1 across t
        }
    }
    __syncthreads();                             // b2: qk visible

    const float mi = msk_sh[i];
    float acc[2] = {0.f, 0.f}, dnm[2] = {0.f, 0.f};
    const short8* ep = (const short8*)esh;

    #pragma unroll
    for (int hf = 0; hf < 2; ++hf) {
        if (hf == 1) {
            __syncthreads();                     // b3: done reading esh half0
            #pragma unroll
            for (int r = 0; r < 4; ++r) {        // stage half 1 (rows 128..255)
                const int cidx = r * 256 + t;
                const int j = cidx >> 3, ch = cidx & 7;
                const float4 f0 = esrc[2048 + 2 * cidx];
                const float4 f1 = esrc[2048 + 2 * cidx + 1];
                union { uint4 u; unsigned short s[8]; } pk;
                pk.s[0]=f2bfu(f0.x); pk.s[1]=f2bfu(f0.y); pk.s[2]=f2bfu(f0.z); pk.s[3]=f2bfu(f0.w);
                pk.s[4]=f2bfu(f1.x); pk.s[5]=f2bfu(f1.y); pk.s[6]=f2bfu(f1.z); pk.s[7]=f2bfu(f1.w);
                edst[j * 8 + (ch ^ (j & 7))] = pk.u;
            }
            __syncthreads();                     // b4: esh half1 visible
        }
        #pragma unroll 2
        for (int s = 0; s < 8; ++s) {
            const int ja = s * 16 + l15;
            const short8 a0 = ep[ja * 8 + ((q4    ) ^ (ja & 7))];  // d 0..31
            const short8 a1 = ep[ja * 8 + ((q4 + 4) ^ (ja & 7))];  // d 32..63
            #pragma unroll
            for (int ct = 0; ct < 2; ++ct) {
                const int g = wave * 2 + ct;
                f32x4 s2 = {0.f,0.f,0.f,0.f}, eE = {0.f,0.f,0.f,0.f};
                s2 = __builtin_amdgcn_mfma_f32_16x16x32_bf16(a0, bfrag[1][ct][0], s2, 0,0,0);
                s2 = __builtin_amdgcn_mfma_f32_16x16x32_bf16(a1, bfrag[1][ct][1], s2, 0,0,0);
                eE = __builtin_amdgcn_mfma_f32_16x16x32_bf16(a0, bfrag[0][ct][0], eE, 0,0,0);
                eE = __builtin_amdgcn_mfma_f32_16x16x32_bf16(a1, bfrag[0][ct][1], eE, 0,0,0);
                const int j0 = hf * 128 + s * 16 + q4 * 4;
                union { float4 v; float a[4]; } v4;
                v4.v = *(const float4*)
                    (Vt + ((size_t)(b * CC) + g * 16 + l15) * NN + j0);
                #pragma unroll
                for (int r = 0; r < 4; ++r) {
                    const int jr = j0 + r;
                    float sc = qk_sh[g * 256 + jr] + s2[r];
                    sc = fminf(5.f, fmaxf(-5.f, sc));
                    const float p  = __expf(sc);
                    const float mm = mi * msk_sh[jr];
                    const float s1 = p * mm;             // mask^1 -> denom
                    dnm[ct] += s1;
                    acc[ct] = fmaf(s1 * mm, v4.a[r] + eE[r], acc[ct]);  // mask^2
                }
            }
        }
    }

    // reduce over quad groups (lanes l, l^16, l^32, l^48 share a column)
    #pragma unroll
    for (int ct = 0; ct < 2; ++ct) {
        float a = acc[ct], d = dnm[ct];
        a += __shfl_xor(a, 16); a += __shfl_xor(a, 32);
        d += __shfl_xor(d, 16); d += __shfl_xor(d, 32);
        acc[ct] = a; dnm[ct] = d;
    }
    if (lane < 32) {
        const int ct = lane >> 4;
        out[(size_t)row * CC + wave * 32 + lane] = acc[ct] / fmaxf(dnm[ct], 1e-6f);
    }
}

extern "C" void kernel_launch(void* const* d_in, const int* in_sizes, int n_in,
                              void* d_out, int out_size, void* d_ws, size_t ws_size,
                              hipStream_t stream)
{
    const float* h    = (const float*)d_in[0];
    const float* e    = (const float*)d_in[1];
    const float* mask = (const float*)d_in[2];
    const float* WQ   = (const float*)d_in[3];
    const float* WK   = (const float*)d_in[4];
    const float* WV   = (const float*)d_in[5];
    const float* WE   = (const float*)d_in[6];
    const float* WE2  = (const float*)d_in[7];

    unsigned short* wfrag = (unsigned short*)d_ws;          // 32 KB
    float* Qw = (float*)((char*)d_ws + 32768);              // 512 KB
    float* Kw = Qw + BB * NN * CC;                          // 512 KB
    float* Vt = Kw + BB * NN * CC;                          // 512 KB (transposed)

    qkv_kernel <<<264,   256, 0, stream>>>(h, WQ, WK, WV, WE, WE2,
                                           Qw, Kw, Vt, wfrag);
    attn_kernel<<<BB*NN, 256, 0, stream>>>(e, mask, wfrag, Qw, Kw, Vt,
                                           (float*)d_out);
}

// Round 9
// 143.440 us; speedup vs baseline: 1.3240x; 1.0325x over previous
//
#include <hip/hip_runtime.h>

// (B,N,DIN,DE,NH,DK) = (4,256,128,64,8,16). Inputs f32, output f32.
#define BB   4
#define NN   256
#define DIN  128
#define DE   64
#define NH   8
#define DK   16
#define CC   128   // NH*DK

typedef __attribute__((ext_vector_type(8))) short short8;   // 8 bf16 = 4 VGPRs
typedef __attribute__((ext_vector_type(4))) float f32x4;

// f32 -> bf16 bits, round-to-nearest-even
__device__ __forceinline__ unsigned short f2bfu(float f) {
    union { float f; unsigned int i; } v; v.f = f;
    unsigned int x = v.i;
    x += 0x7FFFu + ((x >> 16) & 1u);
    return (unsigned short)(x >> 16);
}

// ---------------------------------------------------------------------------
// QKV (+merged wprep): blocks 0..255 compute Q/K/Vt (4 rows each);
// blocks 256..263 convert WE/WE2 into MFMA B-fragment order (wfrag).
// Vt layout: Vt[(b*CC + c)*NN + j]
// ---------------------------------------------------------------------------
__global__ __launch_bounds__(256) void qkv_kernel(
    const float* __restrict__ h, const float* __restrict__ WQ,
    const float* __restrict__ WK, const float* __restrict__ WV,
    const float* __restrict__ WE, const float* __restrict__ WE2,
    float* __restrict__ Qw, float* __restrict__ Kw, float* __restrict__ Vt,
    unsigned short* __restrict__ wfrag)
{
    const int t = threadIdx.x;

    if (blockIdx.x >= 256) {             // ---- wprep part ----
        const int tid  = (blockIdx.x - 256) * 256 + t;   // 0..2047
        const int m    = tid >> 10;
        const int g    = (tid >> 7) & 7;
        const int ks   = (tid >> 6) & 1;
        const int lane = tid & 63;
        const int q4 = lane >> 4, l15 = lane & 15;
        const float* W = m ? WE2 : WE;
        union { uint4 u; unsigned short s[8]; } pk;
        #pragma unroll
        for (int ii = 0; ii < 8; ++ii) {
            const int d = ks * 32 + q4 * 8 + ii;
            pk.s[ii] = f2bfu(W[d * CC + g * 16 + l15]);
        }
        ((uint4*)wfrag)[tid] = pk.u;
        return;
    }

    __shared__ float hsh[4 * DIN];       // 2 KB
    __shared__ float psum[4 * 1536];     // 24 KB
    const int r0 = blockIdx.x * 4;

    hsh[t]       = h[(size_t)r0 * DIN + t];
    hsh[256 + t] = h[(size_t)r0 * DIN + 256 + t];
    __syncthreads();

    const int cp  = t & 63;              // channel pair: c = 2cp, 2cp+1
    const int qtr = t >> 6;              // d in [qtr*32, qtr*32+32)
    float aq[4][2], ak[4][2], av[4][2];
    #pragma unroll
    for (int r = 0; r < 4; ++r)
        aq[r][0]=aq[r][1]=ak[r][0]=ak[r][1]=av[r][0]=av[r][1]=0.f;

    #pragma unroll 4
    for (int dd = 0; dd < 32; ++dd) {
        const int d = qtr * 32 + dd;
        const float2 fq = ((const float2*)WQ)[d * 64 + cp];
        const float2 fk = ((const float2*)WK)[d * 64 + cp];
        const float2 fv = ((const float2*)WV)[d * 64 + cp];
        #pragma unroll
        for (int r = 0; r < 4; ++r) {
            const float hd = hsh[r * DIN + d];
            aq[r][0] = fmaf(hd, fq.x, aq[r][0]); aq[r][1] = fmaf(hd, fq.y, aq[r][1]);
            ak[r][0] = fmaf(hd, fk.x, ak[r][0]); ak[r][1] = fmaf(hd, fk.y, ak[r][1]);
            av[r][0] = fmaf(hd, fv.x, av[r][0]); av[r][1] = fmaf(hd, fv.y, av[r][1]);
        }
    }
    float* pq = psum + qtr * 1536;
    #pragma unroll
    for (int r = 0; r < 4; ++r) {
        pq[r*384       + 2*cp] = aq[r][0]; pq[r*384       + 2*cp+1] = aq[r][1];
        pq[r*384 + 128 + 2*cp] = ak[r][0]; pq[r*384 + 128 + 2*cp+1] = ak[r][1];
        pq[r*384 + 256 + 2*cp] = av[r][0]; pq[r*384 + 256 + 2*cp+1] = av[r][1];
    }
    __syncthreads();

    const int b  = r0 >> 8;
    const int j0 = r0 & 255;
    #pragma unroll
    for (int k = 0; k < 6; ++k) {
        const int o = k * 256 + t;               // 0..1535
        float v = psum[o] + psum[1536 + o] + psum[3072 + o] + psum[4608 + o];
        const int r   = o / 384;
        const int mc  = o - r * 384;
        const int mat = mc >> 7;
        const int c   = mc & 127;
        if      (mat == 0) Qw[(size_t)(r0 + r) * CC + c] = v;
        else if (mat == 1) Kw[(size_t)(r0 + r) * CC + c] = v * 0.25f;  // DK^-0.5
        else               Vt[((size_t)(b * CC) + c) * NN + j0 + r] = v;
    }
}

// ---------------------------------------------------------------------------
// Fused attention. One block (4 waves) per (b,i). LDS 25.5 KB.
// NO min-waves in __launch_bounds__ (rounds 6-7: min-waves>=5 collapsed the
// allocator to 40/48 VGPR + MB-scale scratch spill).
// Half-1 e prefetched into registers (as CONSECUTIVE float4 pairs — round 8's
// stride-256 prefetch layout mismatched the pair-consuming conversion and
// scrambled half-1) before the first barrier; consumed after half-0 compute.
//
// MFMA 16x16x32 bf16 layouts (HW-verified rounds 3-7):
//   A: lane holds A[m=lane&15][k=(lane>>4)*8+ii]
//   B: lane holds B[k=(lane>>4)*8+ii][n=lane&15]
//   C/D: col=lane&15, row=(lane>>4)*4+reg
// ---------------------------------------------------------------------------
__global__ __launch_bounds__(256) void attn_kernel(
    const float* __restrict__ e, const float* __restrict__ maskp,
    const unsigned short* __restrict__ wfrag,
    const float* __restrict__ Qw, const float* __restrict__ Kw,
    const float* __restrict__ Vt, float* __restrict__ out)
{
    __shared__ __align__(16) unsigned short esh[128 * DE];  // 16 KB, swizzled
    __shared__ __align__(16) float qk_sh[NH * NN];          // 8 KB, [h][j]
    __shared__ __align__(16) float msk_sh[NN];              // 1 KB
    __shared__ __align__(16) float qrow_sh[CC];             // 0.5 KB

    const int row  = blockIdx.x;
    const int b    = row >> 8, i = row & 255;
    const int t    = threadIdx.x;
    const int wave = t >> 6, lane = t & 63;
    const int q4   = lane >> 4;
    const int l15  = lane & 15;

    const float4* esrc = (const float4*)(e + (size_t)row * NN * DE);
    uint4* edst = (uint4*)esh;

    // --- B-fragments straight from global (L2-hot) ---
    short8 bfrag[2][2][2];
    {
        const uint4* wf = (const uint4*)wfrag;
        #pragma unroll
        for (int m = 0; m < 2; ++m)
        #pragma unroll
        for (int ct = 0; ct < 2; ++ct) {
            const int g = wave * 2 + ct;
            #pragma unroll
            for (int ks = 0; ks < 2; ++ks) {
                union { uint4 u; short8 s8; } cv;
                cv.u = wf[((m * 8 + g) * 2 + ks) * 64 + lane];
                bfrag[m][ct][ks] = cv.s8;
            }
        }
    }

    if (t < CC) qrow_sh[t] = Qw[(size_t)row * CC + t];
    msk_sh[t] = maskp[b * NN + t];

    // --- stage half 0: e rows 0..127 -> bf16, XOR-swizzled 16B chunks ---
    #pragma unroll
    for (int r = 0; r < 4; ++r) {
        const int cidx = r * 256 + t;            // chunk 0..1023 within half
        const int j = cidx >> 3, ch = cidx & 7;
        const float4 f0 = esrc[2 * cidx];
        const float4 f1 = esrc[2 * cidx + 1];
        union { uint4 u; unsigned short s[8]; } pk;
        pk.s[0]=f2bfu(f0.x); pk.s[1]=f2bfu(f0.y); pk.s[2]=f2bfu(f0.z); pk.s[3]=f2bfu(f0.w);
        pk.s[4]=f2bfu(f1.x); pk.s[5]=f2bfu(f1.y); pk.s[6]=f2bfu(f1.z); pk.s[7]=f2bfu(f1.w);
        edst[j * 8 + (ch ^ (j & 7))] = pk.u;
    }

    // --- issue half-1 loads NOW (same addresses the conversion consumes);
    //     consumed after half-0 compute (~2500 cyc of latency hiding) ---
    float4 pf[8];
    #pragma unroll
    for (int r = 0; r < 4; ++r) {
        const int cidx = r * 256 + t;
        pf[2*r]     = esrc[2048 + 2 * cidx];
        pf[2*r + 1] = esrc[2048 + 2 * cidx + 1];
    }

    __syncthreads();                             // b1: qrow/msk/esh0 visible

    // --- qk[h][j] for ALL 256 j, full f32 (thread t = j) ---
    {
        const float4* kr = (const float4*)(Kw + (size_t)(b * NN + t) * CC);
        #pragma unroll
        for (int hh = 0; hh < NH; ++hh) {
            float s = 0.f;
            #pragma unroll
            for (int p = 0; p < 4; ++p) {
                const float4 kv = kr[hh * 4 + p];
                const int qb = hh * 16 + p * 4;
                s += kv.x * qrow_sh[qb]     + kv.y * qrow_sh[qb + 1]
                   + kv.z * qrow_sh[qb + 2] + kv.w * qrow_sh[qb + 3];
            }
            qk_sh[hh * 256 + t] = s;             // stride-1 across t
        }
    }
    __syncthreads();                             // b2: qk visible

    const float mi = msk_sh[i];
    float acc[2] = {0.f, 0.f}, dnm[2] = {0.f, 0.f};
    const short8* ep = (const short8*)esh;

    #pragma unroll
    for (int hf = 0; hf < 2; ++hf) {
        if (hf == 1) {
            __syncthreads();                     // b3: done reading esh half0
            #pragma unroll
            for (int r = 0; r < 4; ++r) {        // convert prefetched half 1
                const int cidx = r * 256 + t;
                const int j = cidx >> 3, ch = cidx & 7;
                const float4 f0 = pf[2 * r];
                const float4 f1 = pf[2 * r + 1];
                union { uint4 u; unsigned short s[8]; } pk;
                pk.s[0]=f2bfu(f0.x); pk.s[1]=f2bfu(f0.y); pk.s[2]=f2bfu(f0.z); pk.s[3]=f2bfu(f0.w);
                pk.s[4]=f2bfu(f1.x); pk.s[5]=f2bfu(f1.y); pk.s[6]=f2bfu(f1.z); pk.s[7]=f2bfu(f1.w);
                edst[j * 8 + (ch ^ (j & 7))] = pk.u;
            }
            __syncthreads();                     // b4: esh half1 visible
        }
        #pragma unroll 2
        for (int s = 0; s < 8; ++s) {
            const int ja = s * 16 + l15;         // local row within half
            const short8 a0 = ep[ja * 8 + ((q4    ) ^ (ja & 7))];  // d 0..31
            const short8 a1 = ep[ja * 8 + ((q4 + 4) ^ (ja & 7))];  // d 32..63
            const int j0g = hf * 128 + s * 16 + q4 * 4;            // global j
            union { float4 v; float a[4]; } mk4;
            mk4.v = *(const float4*)(msk_sh + j0g);
            #pragma unroll
            for (int ct = 0; ct < 2; ++ct) {
                const int g = wave * 2 + ct;
                f32x4 s2 = {0.f,0.f,0.f,0.f}, eE = {0.f,0.f,0.f,0.f};
                s2 = __builtin_amdgcn_mfma_f32_16x16x32_bf16(a0, bfrag[1][ct][0], s2, 0,0,0);
                s2 = __builtin_amdgcn_mfma_f32_16x16x32_bf16(a1, bfrag[1][ct][1], s2, 0,0,0);
                eE = __builtin_amdgcn_mfma_f32_16x16x32_bf16(a0, bfrag[0][ct][0], eE, 0,0,0);
                eE = __builtin_amdgcn_mfma_f32_16x16x32_bf16(a1, bfrag[0][ct][1], eE, 0,0,0);
                union { float4 v; float a[4]; } v4, qk4;
                v4.v  = *(const float4*)(Vt + ((size_t)(b * CC) + g * 16 + l15) * NN + j0g);
                qk4.v = *(const float4*)(qk_sh + g * 256 + j0g);
                #pragma unroll
                for (int r = 0; r < 4; ++r) {
                    float sc = qk4.a[r] + s2[r];
                    sc = fminf(5.f, fmaxf(-5.f, sc));
                    const float p  = __expf(sc);
                    const float mm = mi * mk4.a[r];
                    const float s1 = p * mm;             // mask^1 -> denom
                    dnm[ct] += s1;
                    acc[ct] = fmaf(s1 * mm, v4.a[r] + eE[r], acc[ct]);  // mask^2
                }
            }
        }
    }

    // reduce over quad groups (lanes l, l^16, l^32, l^48 share a column)
    #pragma unroll
    for (int ct = 0; ct < 2; ++ct) {
        float a = acc[ct], d = dnm[ct];
        a += __shfl_xor(a, 16); a += __shfl_xor(a, 32);
        d += __shfl_xor(d, 16); d += __shfl_xor(d, 32);
        acc[ct] = a; dnm[ct] = d;
    }
    if (lane < 32) {
        const int ct = lane >> 4;
        out[(size_t)row * CC + wave * 32 + lane] = acc[ct] / fmaxf(dnm[ct], 1e-6f);
    }
}

extern "C" void kernel_launch(void* const* d_in, const int* in_sizes, int n_in,
                              void* d_out, int out_size, void* d_ws, size_t ws_size,
                              hipStream_t stream)
{
    const float* h    = (const float*)d_in[0];
    const float* e    = (const float*)d_in[1];
    const float* mask = (const float*)d_in[2];
    const float* WQ   = (const float*)d_in[3];
    const float* WK   = (const float*)d_in[4];
    const float* WV   = (const float*)d_in[5];
    const float* WE   = (const float*)d_in[6];
    const float* WE2  = (const float*)d_in[7];

    unsigned short* wfrag = (unsigned short*)d_ws;          // 32 KB
    float* Qw = (float*)((char*)d_ws + 32768);              // 512 KB
    float* Kw = Qw + BB * NN * CC;                          // 512 KB
    float* Vt = Kw + BB * NN * CC;                          // 512 KB (transposed)

    qkv_kernel <<<264,   256, 0, stream>>>(h, WQ, WK, WV, WE, WE2,
                                           Qw, Kw, Vt, wfrag);
    attn_kernel<<<BB*NN, 256, 0, stream>>>(e, mask, wfrag, Qw, Kw, Vt,
                                           (float*)d_out);
}

// Round 10
// 140.493 us; speedup vs baseline: 1.3518x; 1.0210x over previous
//
#include <hip/hip_runtime.h>

// (B,N,DIN,DE,NH,DK) = (4,256,128,64,8,16). Inputs f32, output f32.
#define BB   4
#define NN   256
#define DIN  128
#define DE   64
#define NH   8
#define DK   16
#define CC   128   // NH*DK

typedef __attribute__((ext_vector_type(8))) short short8;   // 8 bf16 = 4 VGPRs
typedef __attribute__((ext_vector_type(4))) float f32x4;

// f32 -> bf16 bits, round-to-nearest-even
__device__ __forceinline__ unsigned short f2bfu(float f) {
    union { float f; unsigned int i; } v; v.f = f;
    unsigned int x = v.i;
    x += 0x7FFFu + ((x >> 16) & 1u);
    return (unsigned short)(x >> 16);
}

// ---------------------------------------------------------------------------
// QKV (+merged wprep): blocks 0..255 compute Q (row-major) and K^T, V^T
// (transposed: [(b*CC+c)*NN + j]) for 4 rows each; blocks 256..263 convert
// WE/WE2 into MFMA B-fragment order (wfrag).
// K^T makes attn's qk phase fully coalesced (round 9's K row-gather removed).
// ---------------------------------------------------------------------------
__global__ __launch_bounds__(256) void qkv_kernel(
    const float* __restrict__ h, const float* __restrict__ WQ,
    const float* __restrict__ WK, const float* __restrict__ WV,
    const float* __restrict__ WE, const float* __restrict__ WE2,
    float* __restrict__ Qw, float* __restrict__ Kt, float* __restrict__ Vt,
    unsigned short* __restrict__ wfrag)
{
    const int t = threadIdx.x;

    if (blockIdx.x >= 256) {             // ---- wprep part ----
        const int tid  = (blockIdx.x - 256) * 256 + t;   // 0..2047
        const int m    = tid >> 10;
        const int g    = (tid >> 7) & 7;
        const int ks   = (tid >> 6) & 1;
        const int lane = tid & 63;
        const int q4 = lane >> 4, l15 = lane & 15;
        const float* W = m ? WE2 : WE;
        union { uint4 u; unsigned short s[8]; } pk;
        #pragma unroll
        for (int ii = 0; ii < 8; ++ii) {
            const int d = ks * 32 + q4 * 8 + ii;
            pk.s[ii] = f2bfu(W[d * CC + g * 16 + l15]);
        }
        ((uint4*)wfrag)[tid] = pk.u;
        return;
    }

    __shared__ float hsh[4 * DIN];       // 2 KB
    __shared__ float psum[4 * 1536];     // 24 KB
    const int r0 = blockIdx.x * 4;

    hsh[t]       = h[(size_t)r0 * DIN + t];
    hsh[256 + t] = h[(size_t)r0 * DIN + 256 + t];
    __syncthreads();

    const int cp  = t & 63;              // channel pair: c = 2cp, 2cp+1
    const int qtr = t >> 6;              // d in [qtr*32, qtr*32+32)
    float aq[4][2], ak[4][2], av[4][2];
    #pragma unroll
    for (int r = 0; r < 4; ++r)
        aq[r][0]=aq[r][1]=ak[r][0]=ak[r][1]=av[r][0]=av[r][1]=0.f;

    #pragma unroll 4
    for (int dd = 0; dd < 32; ++dd) {
        const int d = qtr * 32 + dd;
        const float2 fq = ((const float2*)WQ)[d * 64 + cp];
        const float2 fk = ((const float2*)WK)[d * 64 + cp];
        const float2 fv = ((const float2*)WV)[d * 64 + cp];
        #pragma unroll
        for (int r = 0; r < 4; ++r) {
            const float hd = hsh[r * DIN + d];
            aq[r][0] = fmaf(hd, fq.x, aq[r][0]); aq[r][1] = fmaf(hd, fq.y, aq[r][1]);
            ak[r][0] = fmaf(hd, fk.x, ak[r][0]); ak[r][1] = fmaf(hd, fk.y, ak[r][1]);
            av[r][0] = fmaf(hd, fv.x, av[r][0]); av[r][1] = fmaf(hd, fv.y, av[r][1]);
        }
    }
    float* pq = psum + qtr * 1536;
    #pragma unroll
    for (int r = 0; r < 4; ++r) {
        pq[r*384       + 2*cp] = aq[r][0]; pq[r*384       + 2*cp+1] = aq[r][1];
        pq[r*384 + 128 + 2*cp] = ak[r][0]; pq[r*384 + 128 + 2*cp+1] = ak[r][1];
        pq[r*384 + 256 + 2*cp] = av[r][0]; pq[r*384 + 256 + 2*cp+1] = av[r][1];
    }
    __syncthreads();

    const int b  = r0 >> 8;
    const int j0 = r0 & 255;
    #pragma unroll
    for (int k = 0; k < 6; ++k) {
        const int o = k * 256 + t;               // 0..1535
        float v = psum[o] + psum[1536 + o] + psum[3072 + o] + psum[4608 + o];
        const int r   = o / 384;
        const int mc  = o - r * 384;
        const int mat = mc >> 7;
        const int c   = mc & 127;
        if      (mat == 0) Qw[(size_t)(r0 + r) * CC + c] = v;
        else if (mat == 1) Kt[((size_t)(b * CC) + c) * NN + j0 + r] = v * 0.25f;
        else               Vt[((size_t)(b * CC) + c) * NN + j0 + r] = v;
    }
}

// ---------------------------------------------------------------------------
// Fused attention. One block (4 waves) per (b,i). ONE barrier.
// LDS = esh 32 KB + qk_sh 8 KB = 40960 B exactly -> 4 blocks/CU.
// All pre-barrier loads are either coalesced (e staging, Kt qk reads) or
// uniform/scalar (Q). Mask/V read post-barrier from global (L1/L2-hot).
// Inter-block overlap (4 resident blocks/CU) hides the staging latency;
// rounds 6-9 showed intra-block phase pipelining only adds serialization.
//
// MFMA 16x16x32 bf16 layouts (HW-verified rounds 3-9):
//   A: lane holds A[m=lane&15][k=(lane>>4)*8+ii]
//   B: lane holds B[k=(lane>>4)*8+ii][n=lane&15]
//   C/D: col=lane&15, row=(lane>>4)*4+reg
// ---------------------------------------------------------------------------
__global__ __launch_bounds__(256) void attn_kernel(
    const float* __restrict__ e, const float* __restrict__ maskp,
    const unsigned short* __restrict__ wfrag,
    const float* __restrict__ Qw, const float* __restrict__ Kt,
    const float* __restrict__ Vt, float* __restrict__ out)
{
    __shared__ __align__(16) unsigned short esh[NN * DE];   // 32 KB, swizzled
    __shared__ __align__(16) float qk_sh[NH * NN];          // 8 KB, [h][j]

    const int row  = blockIdx.x;
    const int b    = row >> 8;
    const int t    = threadIdx.x;
    const int wave = t >> 6, lane = t & 63;
    const int q4   = lane >> 4, l15 = lane & 15;

    // --- B-fragments straight from global (L2-hot) ---
    short8 bfrag[2][2][2];
    {
        const uint4* wf = (const uint4*)wfrag;
        #pragma unroll
        for (int m = 0; m < 2; ++m)
        #pragma unroll
        for (int ct = 0; ct < 2; ++ct) {
            const int g = wave * 2 + ct;
            #pragma unroll
            for (int ks = 0; ks < 2; ++ks) {
                union { uint4 u; short8 s8; } cv;
                cv.u = wf[((m * 8 + g) * 2 + ks) * 64 + lane];
                bfrag[m][ct][ks] = cv.s8;
            }
        }
    }

    // --- stage ALL 256 e-rows f32 -> bf16, XOR-swizzled 16B chunks ---
    {
        const float4* esrc = (const float4*)(e + (size_t)row * NN * DE);
        uint4* edst = (uint4*)esh;
        #pragma unroll
        for (int r = 0; r < 8; ++r) {
            const int cidx = r * 256 + t;        // chunk 0..2047
            const int j = cidx >> 3, ch = cidx & 7;
            const float4 f0 = esrc[2 * cidx];
            const float4 f1 = esrc[2 * cidx + 1];
            union { uint4 u; unsigned short s[8]; } pk;
            pk.s[0]=f2bfu(f0.x); pk.s[1]=f2bfu(f0.y); pk.s[2]=f2bfu(f0.z); pk.s[3]=f2bfu(f0.w);
            pk.s[4]=f2bfu(f1.x); pk.s[5]=f2bfu(f1.y); pk.s[6]=f2bfu(f1.z); pk.s[7]=f2bfu(f1.w);
            edst[j * 8 + (ch ^ (j & 7))] = pk.u;
        }
    }

    // --- qk[h][j]: coalesced Kt columns (thread t = j), uniform Q loads ---
    {
        const float* qp = Qw + (size_t)row * CC;         // uniform -> scalar
        const float* kp = Kt + (size_t)(b * CC) * NN + t;
        #pragma unroll
        for (int hh = 0; hh < NH; ++hh) {
            float s = 0.f;
            #pragma unroll
            for (int kk = 0; kk < DK; ++kk)
                s = fmaf(qp[hh * DK + kk], kp[(size_t)(hh * DK + kk) * NN], s);
            qk_sh[hh * NN + t] = s;              // stride-1 across t
        }
    }
    __syncthreads();                             // THE barrier

    const float mi = maskp[row];
    float acc[2] = {0.f, 0.f}, dnm[2] = {0.f, 0.f};
    const short8* ep = (const short8*)esh;

    #pragma unroll 4
    for (int s = 0; s < 16; ++s) {
        const int ja = s * 16 + l15;
        const short8 a0 = ep[ja * 8 + ((q4    ) ^ (ja & 7))];  // d 0..31
        const short8 a1 = ep[ja * 8 + ((q4 + 4) ^ (ja & 7))];  // d 32..63
        const int j0 = s * 16 + q4 * 4;
        union { float4 v; float a[4]; } mk4;
        mk4.v = *(const float4*)(maskp + b * NN + j0);         // L1-hot
        #pragma unroll
        for (int ct = 0; ct < 2; ++ct) {
            const int g = wave * 2 + ct;
            f32x4 s2 = {0.f,0.f,0.f,0.f}, eE = {0.f,0.f,0.f,0.f};
            s2 = __builtin_amdgcn_mfma_f32_16x16x32_bf16(a0, bfrag[1][ct][0], s2, 0,0,0);
            s2 = __builtin_amdgcn_mfma_f32_16x16x32_bf16(a1, bfrag[1][ct][1], s2, 0,0,0);
            eE = __builtin_amdgcn_mfma_f32_16x16x32_bf16(a0, bfrag[0][ct][0], eE, 0,0,0);
            eE = __builtin_amdgcn_mfma_f32_16x16x32_bf16(a1, bfrag[0][ct][1], eE, 0,0,0);
            union { float4 v; float a[4]; } v4, qk4;
            v4.v  = *(const float4*)(Vt + ((size_t)(b * CC) + g * 16 + l15) * NN + j0);
            qk4.v = *(const float4*)(qk_sh + g * NN + j0);
            #pragma unroll
            for (int r = 0; r < 4; ++r) {
                float sc = qk4.a[r] + s2[r];
                sc = fminf(5.f, fmaxf(-5.f, sc));
                const float p  = __expf(sc);
                const float mm = mi * mk4.a[r];
                const float s1 = p * mm;                 // mask^1 -> denom
                dnm[ct] += s1;
                acc[ct] = fmaf(s1 * mm, v4.a[r] + eE[r], acc[ct]);  // mask^2
            }
        }
    }

    // reduce over quad groups (lanes l, l^16, l^32, l^48 share a column)
    #pragma unroll
    for (int ct = 0; ct < 2; ++ct) {
        float a = acc[ct], d = dnm[ct];
        a += __shfl_xor(a, 16); a += __shfl_xor(a, 32);
        d += __shfl_xor(d, 16); d += __shfl_xor(d, 32);
        acc[ct] = a; dnm[ct] = d;
    }
    if (lane < 32) {
        const int ct = lane >> 4;
        out[(size_t)row * CC + wave * 32 + lane] = acc[ct] / fmaxf(dnm[ct], 1e-6f);
    }
}

extern "C" void kernel_launch(void* const* d_in, const int* in_sizes, int n_in,
                              void* d_out, int out_size, void* d_ws, size_t ws_size,
                              hipStream_t stream)
{
    const float* h    = (const float*)d_in[0];
    const float* e    = (const float*)d_in[1];
    const float* mask = (const float*)d_in[2];
    const float* WQ   = (const float*)d_in[3];
    const float* WK   = (const float*)d_in[4];
    const float* WV   = (const float*)d_in[5];
    const float* WE   = (const float*)d_in[6];
    const float* WE2  = (const float*)d_in[7];

    unsigned short* wfrag = (unsigned short*)d_ws;          // 32 KB
    float* Qw = (float*)((char*)d_ws + 32768);              // 512 KB
    float* Kt = Qw + BB * NN * CC;                          // 512 KB (transposed)
    float* Vt = Kt + BB * NN * CC;                          // 512 KB (transposed)

    qkv_kernel <<<264,   256, 0, stream>>>(h, WQ, WK, WV, WE, WE2,
                                           Qw, Kt, Vt, wfrag);
    attn_kernel<<<BB*NN, 256, 0, stream>>>(e, mask, wfrag, Qw, Kt, Vt,
                                           (float*)d_out);
}